// Round 4
// baseline (114.314 us; speedup 1.0000x reference)
//
#include <hip/hip_runtime.h>

#define TS 20
#define BATCH 8192
#define LOG2E 1.4426950408889634f

typedef _Float16 half8 __attribute__((ext_vector_type(8)));
typedef float f32x4 __attribute__((ext_vector_type(4)));

__device__ __forceinline__ float fexp2(float x) {
#if __has_builtin(__builtin_amdgcn_exp2f)
    return __builtin_amdgcn_exp2f(x);
#else
    return exp2f(x);
#endif
}
// inputs pre-scaled: z' = log2e*z  ->  sig(z) = rcp(1+2^(-z'))
__device__ __forceinline__ float sig2(float zp) {
    return __builtin_amdgcn_rcpf(1.0f + fexp2(-zp));
}
// z' = 2*log2e*z  ->  tanh(z) = 1 - 2*rcp(1+2^(z'))
__device__ __forceinline__ float tanh2(float zp) {
    return 1.0f - 2.0f * __builtin_amdgcn_rcpf(1.0f + fexp2(zp));
}
// row swizzle for 16B LDS units: bijective low-3-bit XOR, spreads lgrp 0/2 writes
__device__ __forceinline__ int swz(int r) { return (r & 7) ^ (((r >> 3) & 1) << 2); }

// ===================== Kernel 1: LSTM layer 1 =====================
// BT=16, grid=512, 8 waves, 2 blocks/CU. K = [h1(0:128) | x(16) | pad(16)], 5 chunks.
// Wave w owns cells [w*16,w*16+16) for all 4 gates. One barrier/step.
extern "C" __global__ __launch_bounds__(512, 4)
void lstm1_kernel(const float* __restrict__ x,
                  const float* __restrict__ Wih1, const float* __restrict__ Whh1,
                  const float* __restrict__ bih1, const float* __restrict__ bhh1,
                  _Float16* __restrict__ out1)   // [TS][BATCH][128] fp16
{
    __shared__ __align__(16) _Float16 Hb[2][16][128];  // 16B unit u of row r stored at u^swz(r)
    __shared__ __align__(16) _Float16 Xb[16][640];     // unit (t*4+lgrp)^swz(r); lgrp>=2 units stay zero

    const int tid  = threadIdx.x;
    const int lane = tid & 63;
    const int w    = tid >> 6;     // 0..7
    const int lrow = lane & 15;
    const int lgrp = lane >> 4;    // 0..3
    const int b0   = blockIdx.x * 16;

    // ---- persistent weights (80 VGPR), pre-scaled by log2e / 2log2e ----
    half8 bf[4][5];
    float bias[4];
#pragma unroll
    for (int g = 0; g < 4; ++g) {
        const float sc = (g == 2) ? 2.0f * LOG2E : LOG2E;
        const int n = g * 128 + w * 16 + lrow;
        bias[g] = (bih1[n] + bhh1[n]) * sc;
#pragma unroll
        for (int ch = 0; ch < 5; ++ch) {
            half8 v;
            if (ch < 4) {
                const float4 p0 = *(const float4*)&Whh1[n * 128 + ch * 32 + lgrp * 8];
                const float4 p1 = *(const float4*)&Whh1[n * 128 + ch * 32 + lgrp * 8 + 4];
                v[0]=(_Float16)(p0.x*sc); v[1]=(_Float16)(p0.y*sc); v[2]=(_Float16)(p0.z*sc); v[3]=(_Float16)(p0.w*sc);
                v[4]=(_Float16)(p1.x*sc); v[5]=(_Float16)(p1.y*sc); v[6]=(_Float16)(p1.z*sc); v[7]=(_Float16)(p1.w*sc);
            } else if (lgrp < 2) {
                const float4 p0 = *(const float4*)&Wih1[n * 16 + lgrp * 8];
                const float4 p1 = *(const float4*)&Wih1[n * 16 + lgrp * 8 + 4];
                v[0]=(_Float16)(p0.x*sc); v[1]=(_Float16)(p0.y*sc); v[2]=(_Float16)(p0.z*sc); v[3]=(_Float16)(p0.w*sc);
                v[4]=(_Float16)(p1.x*sc); v[5]=(_Float16)(p1.y*sc); v[6]=(_Float16)(p1.z*sc); v[7]=(_Float16)(p1.w*sc);
            } else {
#pragma unroll
                for (int j = 0; j < 8; ++j) v[j] = (_Float16)0.0f;
            }
            bf[g][ch] = v;
        }
    }

    // ---- zero LDS, then stage x fp16 (swizzled; pad units remain zero) ----
    for (int i = tid; i < 16 * 640; i += 512) (&Xb[0][0])[i] = (_Float16)0.0f;
    for (int i = tid; i < 2 * 16 * 128; i += 512) (&Hb[0][0][0])[i] = (_Float16)0.0f;
    __syncthreads();
    for (int i = tid; i < 16 * 320; i += 512) {
        const int r = i / 320, k = i % 320;
        const int t = k >> 4, ii = k & 15;
        const int u = (t * 4 + (ii >> 3)) ^ swz(r);
        Xb[r][u * 8 + (ii & 7)] = (_Float16)x[(size_t)(b0 + r) * 320 + k];
    }
    __syncthreads();

    float c1[4] = {0.f, 0.f, 0.f, 0.f};
    const int hu   = w * 2 + (lrow >> 3);   // natural 16B unit of this lane's cell
    const int hlo  = lrow & 7;
    const int sz   = swz(lrow);

    const int srow = (tid >> 4) & 15;       // out-store mapping (tid<256)
    const int sc_  = tid & 15;
    const size_t out_off = (size_t)(b0 + srow) * 128 + sc_ * 8;

    for (int tt = 0; tt < 10; ++tt) {
#pragma unroll
        for (int p = 0; p < 2; ++p) {
            const int t = tt * 2 + p;
            f32x4 z[4];
#pragma unroll
            for (int g = 0; g < 4; ++g) z[g] = (f32x4){bias[g], bias[g], bias[g], bias[g]};
#pragma unroll
            for (int ch = 0; ch < 5; ++ch) {
                half8 a;
                if (ch < 4) a = *(const half8*)&Hb[p ^ 1][lrow][(((ch << 2) | lgrp) ^ sz) * 8];
                else        a = *(const half8*)&Xb[lrow][((((t << 2) | lgrp)) ^ sz) * 8];
#pragma unroll
                for (int g = 0; g < 4; ++g)
                    z[g] = __builtin_amdgcn_mfma_f32_16x16x32_f16(a, bf[g][ch], z[g], 0, 0, 0);
            }
#pragma unroll
            for (int j = 0; j < 4; ++j) {
                const float iv = sig2 (z[0][j]);
                const float fv = sig2 (z[1][j]);
                const float gv = tanh2(z[2][j]);
                const float ov = sig2 (z[3][j]);
                const float cn = fv * c1[j] + iv * gv;
                c1[j] = cn;
                const float h = ov * tanh2(2.0f * LOG2E * cn);
                const int m = (lgrp << 2) | j;               // D row = batch row
                Hb[p][m][((hu ^ swz(m)) << 3) | hlo] = (_Float16)h;
            }
            __syncthreads();
            if (tid < 256) {   // coalesced out1 store; retires during next step
                const half8 v = *(const half8*)&Hb[p][srow][((sc_ ^ swz(srow)) << 3)];
                *(half8*)(out1 + (size_t)t * (BATCH * 128) + out_off) = v;
            }
        }
    }
}

// ===================== Kernel 2: LSTM layer 2 + LN + FC =====================
// BT=16, grid=512, 4 waves, 2 blocks/CU. K = [h1(0:128) | h2(128:192)], 6 chunks.
extern "C" __global__ __launch_bounds__(256, 2)
void lstm2_head_kernel(const _Float16* __restrict__ out1,
                       const float* __restrict__ Wih2, const float* __restrict__ Whh2,
                       const float* __restrict__ bih2, const float* __restrict__ bhh2,
                       const float* __restrict__ gamma, const float* __restrict__ beta,
                       const float* __restrict__ W1fc, const float* __restrict__ b1fc,
                       const float* __restrict__ W2fc, const float* __restrict__ b2fc,
                       float* __restrict__ out)
{
    __shared__ __align__(16) _Float16 A2h1[2][16][128];  // unit c of row r at c^(r&7)
    __shared__ __align__(16) _Float16 A2h2[2][16][76];   // stride 152B (38 dwords) -> bank spread
    __shared__ float h2f[16][68];
    __shared__ float nrm[16][68];

    const int tid  = threadIdx.x;
    const int lane = tid & 63;
    const int w    = tid >> 6;      // 0..3
    const int lrow = lane & 15;
    const int lgrp = lane >> 4;
    const int b0   = blockIdx.x * 16;

    half8 bf2[4][6];
    float bias2[4];
#pragma unroll
    for (int g = 0; g < 4; ++g) {
        const float sc = (g == 2) ? 2.0f * LOG2E : LOG2E;
        const int n = g * 64 + w * 16 + lrow;
        bias2[g] = (bih2[n] + bhh2[n]) * sc;
#pragma unroll
        for (int ch = 0; ch < 6; ++ch) {
            half8 v;
            const float4 p0 = (ch < 4) ? *(const float4*)&Wih2[n * 128 + ch * 32 + lgrp * 8]
                                       : *(const float4*)&Whh2[n * 64 + (ch - 4) * 32 + lgrp * 8];
            const float4 p1 = (ch < 4) ? *(const float4*)&Wih2[n * 128 + ch * 32 + lgrp * 8 + 4]
                                       : *(const float4*)&Whh2[n * 64 + (ch - 4) * 32 + lgrp * 8 + 4];
            v[0]=(_Float16)(p0.x*sc); v[1]=(_Float16)(p0.y*sc); v[2]=(_Float16)(p0.z*sc); v[3]=(_Float16)(p0.w*sc);
            v[4]=(_Float16)(p1.x*sc); v[5]=(_Float16)(p1.y*sc); v[6]=(_Float16)(p1.z*sc); v[7]=(_Float16)(p1.w*sc);
            bf2[g][ch] = v;
        }
    }

    for (int i = tid; i < 2 * 16 * 76; i += 256)
        (&A2h2[0][0][0])[i] = (_Float16)0.0f;

    const int prow = tid >> 4, pck = tid & 15;
    {
        const half8 v = *(const half8*)(out1 + ((size_t)(b0 + prow)) * 128 + pck * 8);
        *(half8*)&A2h1[0][prow][((pck ^ (prow & 7)) * 8)] = v;
    }
    half8 pf1 = *(const half8*)(out1 + ((size_t)1 * BATCH + b0 + prow) * 128 + pck * 8);
    half8 pf2 = *(const half8*)(out1 + ((size_t)2 * BATCH + b0 + prow) * 128 + pck * 8);

    float c2[4] = {0.f, 0.f, 0.f, 0.f};
    __syncthreads();

    int cur = 0;
    for (int t = 0; t < TS; ++t) {
        const int nxt = cur ^ 1;
        f32x4 z[4];
#pragma unroll
        for (int g = 0; g < 4; ++g) z[g] = (f32x4){bias2[g], bias2[g], bias2[g], bias2[g]};
#pragma unroll
        for (int ch = 0; ch < 6; ++ch) {
            half8 a;
            if (ch < 4) a = *(const half8*)&A2h1[cur][lrow][(((ch << 2) | lgrp) ^ (lrow & 7)) * 8];
            else        a = *(const half8*)&A2h2[cur][lrow][(ch - 4) * 32 + lgrp * 8];
#pragma unroll
            for (int g = 0; g < 4; ++g)
                z[g] = __builtin_amdgcn_mfma_f32_16x16x32_f16(a, bf2[g][ch], z[g], 0, 0, 0);
        }
        const int cell = w * 16 + lrow;
#pragma unroll
        for (int j = 0; j < 4; ++j) {
            const float iv = sig2 (z[0][j]);
            const float fv = sig2 (z[1][j]);
            const float gv = tanh2(z[2][j]);
            const float ov = sig2 (z[3][j]);
            const float cn = fv * c2[j] + iv * gv;
            c2[j] = cn;
            const float h = ov * tanh2(2.0f * LOG2E * cn);
            const int m = (lgrp << 2) | j;
            A2h2[nxt][m][cell] = (_Float16)h;
            if (t == TS - 1) h2f[m][cell] = h;
        }
        if (t + 1 < TS)
            *(half8*)&A2h1[nxt][prow][((pck ^ (prow & 7)) * 8)] = pf1;
        pf1 = pf2;
        if (t + 3 < TS)
            pf2 = *(const half8*)(out1 + ((size_t)(t + 3) * BATCH + b0 + prow) * 128 + pck * 8);
        __syncthreads();
        cur = nxt;
    }

    // ---- epilogue: LayerNorm + FC1(relu) + FC2 ----
    {
        const int m = tid >> 4, q = tid & 15;
        const float v0 = h2f[m][q * 4 + 0];
        const float v1 = h2f[m][q * 4 + 1];
        const float v2 = h2f[m][q * 4 + 2];
        const float v3 = h2f[m][q * 4 + 3];
        float s = v0 + v1 + v2 + v3;
        s += __shfl_xor(s, 1); s += __shfl_xor(s, 2);
        s += __shfl_xor(s, 4); s += __shfl_xor(s, 8);
        const float mean = s * (1.0f / 64.0f);
        const float d0 = v0 - mean, d1 = v1 - mean, d2 = v2 - mean, d3 = v3 - mean;
        float vs = d0 * d0 + d1 * d1 + d2 * d2 + d3 * d3;
        vs += __shfl_xor(vs, 1); vs += __shfl_xor(vs, 2);
        vs += __shfl_xor(vs, 4); vs += __shfl_xor(vs, 8);
        const float rstd = rsqrtf(vs * (1.0f / 64.0f) + 1e-5f);
        const int i0 = q * 4;
        nrm[m][i0 + 0] = d0 * rstd * gamma[i0 + 0] + beta[i0 + 0];
        nrm[m][i0 + 1] = d1 * rstd * gamma[i0 + 1] + beta[i0 + 1];
        nrm[m][i0 + 2] = d2 * rstd * gamma[i0 + 2] + beta[i0 + 2];
        nrm[m][i0 + 3] = d3 * rstd * gamma[i0 + 3] + beta[i0 + 3];
    }
    __syncthreads();
    {
        const int o = tid & 31;
        const int mbase = tid >> 5;   // 0..7
#pragma unroll
        for (int rr = 0; rr < 2; ++rr) {
            const int m = mbase + rr * 8;
            float acc = b1fc[o];
#pragma unroll 8
            for (int k = 0; k < 64; ++k) acc += nrm[m][k] * W1fc[o * 64 + k];
            const float hv = fmaxf(acc, 0.0f);
            float p = hv * W2fc[o];
            p += __shfl_xor(p, 1); p += __shfl_xor(p, 2);
            p += __shfl_xor(p, 4); p += __shfl_xor(p, 8); p += __shfl_xor(p, 16);
            if (o == 0) out[b0 + m] = p + b2fc[0];
        }
    }
}

extern "C" void kernel_launch(void* const* d_in, const int* in_sizes, int n_in,
                              void* d_out, int out_size, void* d_ws, size_t ws_size,
                              hipStream_t stream) {
    (void)in_sizes; (void)n_in; (void)ws_size; (void)out_size;
    const float* x_p    = (const float*)d_in[0];
    const float* Wih1_p = (const float*)d_in[1];
    const float* Whh1_p = (const float*)d_in[2];
    const float* bih1_p = (const float*)d_in[3];
    const float* bhh1_p = (const float*)d_in[4];
    const float* Wih2_p = (const float*)d_in[5];
    const float* Whh2_p = (const float*)d_in[6];
    const float* bih2_p = (const float*)d_in[7];
    const float* bhh2_p = (const float*)d_in[8];
    const float* gamma_p = (const float*)d_in[9];
    const float* beta_p  = (const float*)d_in[10];
    const float* W1_p   = (const float*)d_in[11];
    const float* b1_p   = (const float*)d_in[12];
    const float* W2_p   = (const float*)d_in[13];
    const float* b2_p   = (const float*)d_in[14];
    float* out_p = (float*)d_out;

    _Float16* out1 = (_Float16*)d_ws;   // 20*8192*128*2 = 41.9 MB

    lstm1_kernel<<<dim3(BATCH / 16), dim3(512), 0, stream>>>(
        x_p, Wih1_p, Whh1_p, bih1_p, bhh1_p, out1);
    lstm2_head_kernel<<<dim3(BATCH / 16), dim3(256), 0, stream>>>(
        out1, Wih2_p, Whh2_p, bih2_p, bhh2_p,
        gamma_p, beta_p, W1_p, b1_p, W2_p, b2_p, out_p);
}

// Round 5
// 99.816 us; speedup vs baseline: 1.1452x; 1.1452x over previous
//
#include <hip/hip_runtime.h>

#define TS 20
#define BATCH 8192
#define LOG2E 1.4426950408889634f

typedef _Float16 half8 __attribute__((ext_vector_type(8)));
typedef float f32x4 __attribute__((ext_vector_type(4)));

__device__ __forceinline__ float fexp2(float x) {
#if __has_builtin(__builtin_amdgcn_exp2f)
    return __builtin_amdgcn_exp2f(x);
#else
    return exp2f(x);
#endif
}
// inputs pre-scaled: z' = log2e*z  ->  sig(z) = rcp(1+2^(-z'))
__device__ __forceinline__ float sig2(float zp) {
    return __builtin_amdgcn_rcpf(1.0f + fexp2(-zp));
}
// z' = 2*log2e*z  ->  tanh(z) = 1 - 2*rcp(1+2^(z'))
__device__ __forceinline__ float tanh2(float zp) {
    return 1.0f - 2.0f * __builtin_amdgcn_rcpf(1.0f + fexp2(zp));
}
// row swizzle for 16B LDS units
__device__ __forceinline__ int swz(int r) { return (r & 7) ^ (((r >> 3) & 1) << 2); }

// ===================== Kernel 1: LSTM layer 1 =====================
// BT=16, grid=512, 8 waves. __launch_bounds__(512,2): 2nd arg is CUDA-style
// blocks/CU on hipcc -> VGPR cap 128 (measured: (512,4) caps at 64 and SPILLS).
// 2 blocks/CU co-resident at VGPR<=128 hides barrier/latency stalls.
extern "C" __global__ __launch_bounds__(512, 2)
void lstm1_kernel(const float* __restrict__ x,
                  const float* __restrict__ Wih1, const float* __restrict__ Whh1,
                  const float* __restrict__ bih1, const float* __restrict__ bhh1,
                  _Float16* __restrict__ out1)   // [TS][BATCH][128] fp16
{
    __shared__ __align__(16) _Float16 Hb[2][16][128];  // 16B unit u of row r stored at u^swz(r)
    __shared__ __align__(16) _Float16 Xb[16][640];     // unit (t*4+lgrp)^swz(r); lgrp>=2 units stay zero

    const int tid  = threadIdx.x;
    const int lane = tid & 63;
    const int w    = tid >> 6;     // 0..7
    const int lrow = lane & 15;
    const int lgrp = lane >> 4;    // 0..3
    const int b0   = blockIdx.x * 16;

    // ---- persistent weights (80 VGPR), pre-scaled by log2e / 2log2e ----
    half8 bf[4][5];
    float bias[4];
#pragma unroll
    for (int g = 0; g < 4; ++g) {
        const float sc = (g == 2) ? 2.0f * LOG2E : LOG2E;
        const int n = g * 128 + w * 16 + lrow;
        bias[g] = (bih1[n] + bhh1[n]) * sc;
#pragma unroll
        for (int ch = 0; ch < 5; ++ch) {
            half8 v;
            if (ch < 4) {
                const float4 p0 = *(const float4*)&Whh1[n * 128 + ch * 32 + lgrp * 8];
                const float4 p1 = *(const float4*)&Whh1[n * 128 + ch * 32 + lgrp * 8 + 4];
                v[0]=(_Float16)(p0.x*sc); v[1]=(_Float16)(p0.y*sc); v[2]=(_Float16)(p0.z*sc); v[3]=(_Float16)(p0.w*sc);
                v[4]=(_Float16)(p1.x*sc); v[5]=(_Float16)(p1.y*sc); v[6]=(_Float16)(p1.z*sc); v[7]=(_Float16)(p1.w*sc);
            } else if (lgrp < 2) {
                const float4 p0 = *(const float4*)&Wih1[n * 16 + lgrp * 8];
                const float4 p1 = *(const float4*)&Wih1[n * 16 + lgrp * 8 + 4];
                v[0]=(_Float16)(p0.x*sc); v[1]=(_Float16)(p0.y*sc); v[2]=(_Float16)(p0.z*sc); v[3]=(_Float16)(p0.w*sc);
                v[4]=(_Float16)(p1.x*sc); v[5]=(_Float16)(p1.y*sc); v[6]=(_Float16)(p1.z*sc); v[7]=(_Float16)(p1.w*sc);
            } else {
#pragma unroll
                for (int j = 0; j < 8; ++j) v[j] = (_Float16)0.0f;
            }
            bf[g][ch] = v;
        }
    }

    // ---- zero LDS, then stage x fp16 (swizzled; pad units remain zero) ----
    for (int i = tid; i < 16 * 640; i += 512) (&Xb[0][0])[i] = (_Float16)0.0f;
    for (int i = tid; i < 2 * 16 * 128; i += 512) (&Hb[0][0][0])[i] = (_Float16)0.0f;
    __syncthreads();
    for (int i = tid; i < 16 * 320; i += 512) {
        const int r = i / 320, k = i % 320;
        const int t = k >> 4, ii = k & 15;
        const int u = (t * 4 + (ii >> 3)) ^ swz(r);
        Xb[r][u * 8 + (ii & 7)] = (_Float16)x[(size_t)(b0 + r) * 320 + k];
    }
    __syncthreads();

    float c1[4] = {0.f, 0.f, 0.f, 0.f};
    const int hu   = w * 2 + (lrow >> 3);   // natural 16B unit of this lane's cell
    const int hlo  = lrow & 7;
    const int sz   = swz(lrow);

    const int srow = (tid >> 4) & 15;       // out-store mapping (tid<256)
    const int sc_  = tid & 15;
    const size_t out_off = (size_t)(b0 + srow) * 128 + sc_ * 8;

    for (int tt = 0; tt < 10; ++tt) {
#pragma unroll
        for (int p = 0; p < 2; ++p) {
            const int t = tt * 2 + p;
            f32x4 z[4];
#pragma unroll
            for (int g = 0; g < 4; ++g) z[g] = (f32x4){bias[g], bias[g], bias[g], bias[g]};
#pragma unroll
            for (int ch = 0; ch < 5; ++ch) {
                half8 a;
                if (ch < 4) a = *(const half8*)&Hb[p ^ 1][lrow][(((ch << 2) | lgrp) ^ sz) * 8];
                else        a = *(const half8*)&Xb[lrow][((((t << 2) | lgrp)) ^ sz) * 8];
#pragma unroll
                for (int g = 0; g < 4; ++g)
                    z[g] = __builtin_amdgcn_mfma_f32_16x16x32_f16(a, bf[g][ch], z[g], 0, 0, 0);
            }
#pragma unroll
            for (int j = 0; j < 4; ++j) {
                const float iv = sig2 (z[0][j]);
                const float fv = sig2 (z[1][j]);
                const float gv = tanh2(z[2][j]);
                const float ov = sig2 (z[3][j]);
                const float cn = fv * c1[j] + iv * gv;
                c1[j] = cn;
                const float h = ov * tanh2(2.0f * LOG2E * cn);
                const int m = (lgrp << 2) | j;               // D row = batch row
                Hb[p][m][((hu ^ swz(m)) << 3) | hlo] = (_Float16)h;
            }
            __syncthreads();
            if (tid < 256) {   // coalesced out1 store; retires during next step
                const half8 v = *(const half8*)&Hb[p][srow][((sc_ ^ swz(srow)) << 3)];
                *(half8*)(out1 + (size_t)t * (BATCH * 128) + out_off) = v;
            }
        }
    }
}

// ===================== Kernel 2: LSTM layer 2 + LN + FC =====================
// BT=16, grid=512, 4 waves, 2 blocks/CU. K = [h1(0:128) | h2(128:192)], 6 chunks.
extern "C" __global__ __launch_bounds__(256, 2)
void lstm2_head_kernel(const _Float16* __restrict__ out1,
                       const float* __restrict__ Wih2, const float* __restrict__ Whh2,
                       const float* __restrict__ bih2, const float* __restrict__ bhh2,
                       const float* __restrict__ gamma, const float* __restrict__ beta,
                       const float* __restrict__ W1fc, const float* __restrict__ b1fc,
                       const float* __restrict__ W2fc, const float* __restrict__ b2fc,
                       float* __restrict__ out)
{
    __shared__ __align__(16) _Float16 A2h1[2][16][128];  // unit c of row r at c^(r&7)
    __shared__ __align__(16) _Float16 A2h2[2][16][76];   // stride 152B -> bank spread
    __shared__ float h2f[16][68];
    __shared__ float nrm[16][68];

    const int tid  = threadIdx.x;
    const int lane = tid & 63;
    const int w    = tid >> 6;      // 0..3
    const int lrow = lane & 15;
    const int lgrp = lane >> 4;
    const int b0   = blockIdx.x * 16;

    half8 bf2[4][6];
    float bias2[4];
#pragma unroll
    for (int g = 0; g < 4; ++g) {
        const float sc = (g == 2) ? 2.0f * LOG2E : LOG2E;
        const int n = g * 64 + w * 16 + lrow;
        bias2[g] = (bih2[n] + bhh2[n]) * sc;
#pragma unroll
        for (int ch = 0; ch < 6; ++ch) {
            half8 v;
            const float4 p0 = (ch < 4) ? *(const float4*)&Wih2[n * 128 + ch * 32 + lgrp * 8]
                                       : *(const float4*)&Whh2[n * 64 + (ch - 4) * 32 + lgrp * 8];
            const float4 p1 = (ch < 4) ? *(const float4*)&Wih2[n * 128 + ch * 32 + lgrp * 8 + 4]
                                       : *(const float4*)&Whh2[n * 64 + (ch - 4) * 32 + lgrp * 8 + 4];
            v[0]=(_Float16)(p0.x*sc); v[1]=(_Float16)(p0.y*sc); v[2]=(_Float16)(p0.z*sc); v[3]=(_Float16)(p0.w*sc);
            v[4]=(_Float16)(p1.x*sc); v[5]=(_Float16)(p1.y*sc); v[6]=(_Float16)(p1.z*sc); v[7]=(_Float16)(p1.w*sc);
            bf2[g][ch] = v;
        }
    }

    for (int i = tid; i < 2 * 16 * 76; i += 256)
        (&A2h2[0][0][0])[i] = (_Float16)0.0f;

    const int prow = tid >> 4, pck = tid & 15;
    {
        const half8 v = *(const half8*)(out1 + ((size_t)(b0 + prow)) * 128 + pck * 8);
        *(half8*)&A2h1[0][prow][((pck ^ (prow & 7)) * 8)] = v;
    }
    half8 pf1 = *(const half8*)(out1 + ((size_t)1 * BATCH + b0 + prow) * 128 + pck * 8);
    half8 pf2 = *(const half8*)(out1 + ((size_t)2 * BATCH + b0 + prow) * 128 + pck * 8);

    float c2[4] = {0.f, 0.f, 0.f, 0.f};
    __syncthreads();

    int cur = 0;
    for (int t = 0; t < TS; ++t) {
        const int nxt = cur ^ 1;
        f32x4 z[4];
#pragma unroll
        for (int g = 0; g < 4; ++g) z[g] = (f32x4){bias2[g], bias2[g], bias2[g], bias2[g]};
#pragma unroll
        for (int ch = 0; ch < 6; ++ch) {
            half8 a;
            if (ch < 4) a = *(const half8*)&A2h1[cur][lrow][(((ch << 2) | lgrp) ^ (lrow & 7)) * 8];
            else        a = *(const half8*)&A2h2[cur][lrow][(ch - 4) * 32 + lgrp * 8];
#pragma unroll
            for (int g = 0; g < 4; ++g)
                z[g] = __builtin_amdgcn_mfma_f32_16x16x32_f16(a, bf2[g][ch], z[g], 0, 0, 0);
        }
        const int cell = w * 16 + lrow;
#pragma unroll
        for (int j = 0; j < 4; ++j) {
            const float iv = sig2 (z[0][j]);
            const float fv = sig2 (z[1][j]);
            const float gv = tanh2(z[2][j]);
            const float ov = sig2 (z[3][j]);
            const float cn = fv * c2[j] + iv * gv;
            c2[j] = cn;
            const float h = ov * tanh2(2.0f * LOG2E * cn);
            const int m = (lgrp << 2) | j;
            A2h2[nxt][m][cell] = (_Float16)h;
            if (t == TS - 1) h2f[m][cell] = h;
        }
        if (t + 1 < TS)
            *(half8*)&A2h1[nxt][prow][((pck ^ (prow & 7)) * 8)] = pf1;
        pf1 = pf2;
        if (t + 3 < TS)
            pf2 = *(const half8*)(out1 + ((size_t)(t + 3) * BATCH + b0 + prow) * 128 + pck * 8);
        __syncthreads();
        cur = nxt;
    }

    // ---- epilogue: LayerNorm + FC1(relu) + FC2 ----
    {
        const int m = tid >> 4, q = tid & 15;
        const float v0 = h2f[m][q * 4 + 0];
        const float v1 = h2f[m][q * 4 + 1];
        const float v2 = h2f[m][q * 4 + 2];
        const float v3 = h2f[m][q * 4 + 3];
        float s = v0 + v1 + v2 + v3;
        s += __shfl_xor(s, 1); s += __shfl_xor(s, 2);
        s += __shfl_xor(s, 4); s += __shfl_xor(s, 8);
        const float mean = s * (1.0f / 64.0f);
        const float d0 = v0 - mean, d1 = v1 - mean, d2 = v2 - mean, d3 = v3 - mean;
        float vs = d0 * d0 + d1 * d1 + d2 * d2 + d3 * d3;
        vs += __shfl_xor(vs, 1); vs += __shfl_xor(vs, 2);
        vs += __shfl_xor(vs, 4); vs += __shfl_xor(vs, 8);
        const float rstd = rsqrtf(vs * (1.0f / 64.0f) + 1e-5f);
        const int i0 = q * 4;
        nrm[m][i0 + 0] = d0 * rstd * gamma[i0 + 0] + beta[i0 + 0];
        nrm[m][i0 + 1] = d1 * rstd * gamma[i0 + 1] + beta[i0 + 1];
        nrm[m][i0 + 2] = d2 * rstd * gamma[i0 + 2] + beta[i0 + 2];
        nrm[m][i0 + 3] = d3 * rstd * gamma[i0 + 3] + beta[i0 + 3];
    }
    __syncthreads();
    {
        const int o = tid & 31;
        const int mbase = tid >> 5;   // 0..7
#pragma unroll
        for (int rr = 0; rr < 2; ++rr) {
            const int m = mbase + rr * 8;
            float acc = b1fc[o];
#pragma unroll 8
            for (int k = 0; k < 64; ++k) acc += nrm[m][k] * W1fc[o * 64 + k];
            const float hv = fmaxf(acc, 0.0f);
            float p = hv * W2fc[o];
            p += __shfl_xor(p, 1); p += __shfl_xor(p, 2);
            p += __shfl_xor(p, 4); p += __shfl_xor(p, 8); p += __shfl_xor(p, 16);
            if (o == 0) out[b0 + m] = p + b2fc[0];
        }
    }
}

extern "C" void kernel_launch(void* const* d_in, const int* in_sizes, int n_in,
                              void* d_out, int out_size, void* d_ws, size_t ws_size,
                              hipStream_t stream) {
    (void)in_sizes; (void)n_in; (void)ws_size; (void)out_size;
    const float* x_p    = (const float*)d_in[0];
    const float* Wih1_p = (const float*)d_in[1];
    const float* Whh1_p = (const float*)d_in[2];
    const float* bih1_p = (const float*)d_in[3];
    const float* bhh1_p = (const float*)d_in[4];
    const float* Wih2_p = (const float*)d_in[5];
    const float* Whh2_p = (const float*)d_in[6];
    const float* bih2_p = (const float*)d_in[7];
    const float* bhh2_p = (const float*)d_in[8];
    const float* gamma_p = (const float*)d_in[9];
    const float* beta_p  = (const float*)d_in[10];
    const float* W1_p   = (const float*)d_in[11];
    const float* b1_p   = (const float*)d_in[12];
    const float* W2_p   = (const float*)d_in[13];
    const float* b2_p   = (const float*)d_in[14];
    float* out_p = (float*)d_out;

    _Float16* out1 = (_Float16*)d_ws;   // 20*8192*128*2 = 41.9 MB

    lstm1_kernel<<<dim3(BATCH / 16), dim3(512), 0, stream>>>(
        x_p, Wih1_p, Whh1_p, bih1_p, bhh1_p, out1);
    lstm2_head_kernel<<<dim3(BATCH / 16), dim3(256), 0, stream>>>(
        out1, Wih2_p, Whh2_p, bih2_p, bhh2_p,
        gamma_p, beta_p, W1_p, b1_p, W2_p, b2_p, out_p);
}

// Round 6
// 97.414 us; speedup vs baseline: 1.1735x; 1.0247x over previous
//
#include <hip/hip_runtime.h>

#define TS 20
#define BATCH 8192
#define LOG2E 1.4426950408889634f

typedef _Float16 half8 __attribute__((ext_vector_type(8)));
typedef float f32x4 __attribute__((ext_vector_type(4)));

__device__ __forceinline__ float fexp2(float x) {
#if __has_builtin(__builtin_amdgcn_exp2f)
    return __builtin_amdgcn_exp2f(x);
#else
    return exp2f(x);
#endif
}
// inputs pre-scaled: z' = log2e*z  ->  sig(z) = rcp(1+2^(-z'))
__device__ __forceinline__ float sig2(float zp) {
    return __builtin_amdgcn_rcpf(1.0f + fexp2(-zp));
}
// z' = 2*log2e*z  ->  tanh(z) = 1 - 2*rcp(1+2^(z'))
__device__ __forceinline__ float tanh2(float zp) {
    return 1.0f - 2.0f * __builtin_amdgcn_rcpf(1.0f + fexp2(zp));
}
// row swizzle for 16B LDS units
__device__ __forceinline__ int swz(int r) { return (r & 7) ^ (((r >> 3) & 1) << 2); }

// ===================== Kernel 1: LSTM layer 1 =====================
// BT=16, grid=512, 8 waves. NO 2nd launch_bounds arg: measured across R3-R5,
// the 2nd arg acts as a waves/EU ceiling on this hipcc (occupancy tracked it
// exactly: (512,4)->41%, (512,2)->20% = 1 block/CU in 2 rounds). Free
// allocation keeps VGPR ~84 -> 5 waves/SIMD HW limit -> 2 blocks/CU.
extern "C" __global__ __launch_bounds__(512)
void lstm1_kernel(const float* __restrict__ x,
                  const float* __restrict__ Wih1, const float* __restrict__ Whh1,
                  const float* __restrict__ bih1, const float* __restrict__ bhh1,
                  _Float16* __restrict__ out1)   // [TS][BATCH][128] fp16
{
    __shared__ __align__(16) _Float16 Hb[2][16][128];  // 16B unit u of row r stored at u^swz(r)
    __shared__ __align__(16) _Float16 Xb[16][640];     // unit (t*4+lgrp)^swz(r); lgrp>=2 units stay zero

    const int tid  = threadIdx.x;
    const int lane = tid & 63;
    const int w    = tid >> 6;     // 0..7
    const int lrow = lane & 15;
    const int lgrp = lane >> 4;    // 0..3
    const int b0   = blockIdx.x * 16;

    // ---- persistent weights (80 VGPR), pre-scaled by log2e / 2log2e ----
    half8 bf[4][5];
    float bias[4];
#pragma unroll
    for (int g = 0; g < 4; ++g) {
        const float sc = (g == 2) ? 2.0f * LOG2E : LOG2E;
        const int n = g * 128 + w * 16 + lrow;
        bias[g] = (bih1[n] + bhh1[n]) * sc;
#pragma unroll
        for (int ch = 0; ch < 5; ++ch) {
            half8 v;
            if (ch < 4) {
                const float4 p0 = *(const float4*)&Whh1[n * 128 + ch * 32 + lgrp * 8];
                const float4 p1 = *(const float4*)&Whh1[n * 128 + ch * 32 + lgrp * 8 + 4];
                v[0]=(_Float16)(p0.x*sc); v[1]=(_Float16)(p0.y*sc); v[2]=(_Float16)(p0.z*sc); v[3]=(_Float16)(p0.w*sc);
                v[4]=(_Float16)(p1.x*sc); v[5]=(_Float16)(p1.y*sc); v[6]=(_Float16)(p1.z*sc); v[7]=(_Float16)(p1.w*sc);
            } else if (lgrp < 2) {
                const float4 p0 = *(const float4*)&Wih1[n * 16 + lgrp * 8];
                const float4 p1 = *(const float4*)&Wih1[n * 16 + lgrp * 8 + 4];
                v[0]=(_Float16)(p0.x*sc); v[1]=(_Float16)(p0.y*sc); v[2]=(_Float16)(p0.z*sc); v[3]=(_Float16)(p0.w*sc);
                v[4]=(_Float16)(p1.x*sc); v[5]=(_Float16)(p1.y*sc); v[6]=(_Float16)(p1.z*sc); v[7]=(_Float16)(p1.w*sc);
            } else {
#pragma unroll
                for (int j = 0; j < 8; ++j) v[j] = (_Float16)0.0f;
            }
            bf[g][ch] = v;
        }
    }

    // ---- zero LDS, then stage x fp16 (swizzled; pad units remain zero) ----
    for (int i = tid; i < 16 * 640; i += 512) (&Xb[0][0])[i] = (_Float16)0.0f;
    for (int i = tid; i < 2 * 16 * 128; i += 512) (&Hb[0][0][0])[i] = (_Float16)0.0f;
    __syncthreads();
    for (int i = tid; i < 16 * 320; i += 512) {
        const int r = i / 320, k = i % 320;
        const int t = k >> 4, ii = k & 15;
        const int u = (t * 4 + (ii >> 3)) ^ swz(r);
        Xb[r][u * 8 + (ii & 7)] = (_Float16)x[(size_t)(b0 + r) * 320 + k];
    }
    __syncthreads();

    float c1[4] = {0.f, 0.f, 0.f, 0.f};
    const int hu   = w * 2 + (lrow >> 3);   // natural 16B unit of this lane's cell
    const int hlo  = lrow & 7;
    const int sz   = swz(lrow);

    const int srow = (tid >> 4) & 15;       // out-store mapping (tid<256)
    const int sc_  = tid & 15;
    const size_t out_off = (size_t)(b0 + srow) * 128 + sc_ * 8;

    for (int tt = 0; tt < 10; ++tt) {
#pragma unroll
        for (int p = 0; p < 2; ++p) {
            const int t = tt * 2 + p;
            f32x4 z[4];
#pragma unroll
            for (int g = 0; g < 4; ++g) z[g] = (f32x4){bias[g], bias[g], bias[g], bias[g]};
#pragma unroll
            for (int ch = 0; ch < 5; ++ch) {
                half8 a;
                if (ch < 4) a = *(const half8*)&Hb[p ^ 1][lrow][(((ch << 2) | lgrp) ^ sz) * 8];
                else        a = *(const half8*)&Xb[lrow][((((t << 2) | lgrp)) ^ sz) * 8];
#pragma unroll
                for (int g = 0; g < 4; ++g)
                    z[g] = __builtin_amdgcn_mfma_f32_16x16x32_f16(a, bf[g][ch], z[g], 0, 0, 0);
            }
#pragma unroll
            for (int j = 0; j < 4; ++j) {
                const float iv = sig2 (z[0][j]);
                const float fv = sig2 (z[1][j]);
                const float gv = tanh2(z[2][j]);
                const float ov = sig2 (z[3][j]);
                const float cn = fv * c1[j] + iv * gv;
                c1[j] = cn;
                const float h = ov * tanh2(2.0f * LOG2E * cn);
                const int m = (lgrp << 2) | j;               // D row = batch row
                Hb[p][m][((hu ^ swz(m)) << 3) | hlo] = (_Float16)h;
            }
            __syncthreads();
            if (tid < 256) {   // coalesced out1 store; retires during next step
                const half8 v = *(const half8*)&Hb[p][srow][((sc_ ^ swz(srow)) << 3)];
                *(half8*)(out1 + (size_t)t * (BATCH * 128) + out_off) = v;
            }
        }
    }
}

// ===================== Kernel 2: LSTM layer 2 + LN + FC =====================
// BT=16, grid=512, 4 waves. K = [h1(0:128) | h2(128:192)], 6 chunks.
extern "C" __global__ __launch_bounds__(256)
void lstm2_head_kernel(const _Float16* __restrict__ out1,
                       const float* __restrict__ Wih2, const float* __restrict__ Whh2,
                       const float* __restrict__ bih2, const float* __restrict__ bhh2,
                       const float* __restrict__ gamma, const float* __restrict__ beta,
                       const float* __restrict__ W1fc, const float* __restrict__ b1fc,
                       const float* __restrict__ W2fc, const float* __restrict__ b2fc,
                       float* __restrict__ out)
{
    __shared__ __align__(16) _Float16 A2h1[2][16][128];  // unit c of row r at c^(r&7)
    __shared__ __align__(16) _Float16 A2h2[2][16][76];   // stride 152B -> bank spread
    __shared__ float h2f[16][68];
    __shared__ float nrm[16][68];

    const int tid  = threadIdx.x;
    const int lane = tid & 63;
    const int w    = tid >> 6;      // 0..3
    const int lrow = lane & 15;
    const int lgrp = lane >> 4;
    const int b0   = blockIdx.x * 16;

    half8 bf2[4][6];
    float bias2[4];
#pragma unroll
    for (int g = 0; g < 4; ++g) {
        const float sc = (g == 2) ? 2.0f * LOG2E : LOG2E;
        const int n = g * 64 + w * 16 + lrow;
        bias2[g] = (bih2[n] + bhh2[n]) * sc;
#pragma unroll
        for (int ch = 0; ch < 6; ++ch) {
            half8 v;
            const float4 p0 = (ch < 4) ? *(const float4*)&Wih2[n * 128 + ch * 32 + lgrp * 8]
                                       : *(const float4*)&Whh2[n * 64 + (ch - 4) * 32 + lgrp * 8];
            const float4 p1 = (ch < 4) ? *(const float4*)&Wih2[n * 128 + ch * 32 + lgrp * 8 + 4]
                                       : *(const float4*)&Whh2[n * 64 + (ch - 4) * 32 + lgrp * 8 + 4];
            v[0]=(_Float16)(p0.x*sc); v[1]=(_Float16)(p0.y*sc); v[2]=(_Float16)(p0.z*sc); v[3]=(_Float16)(p0.w*sc);
            v[4]=(_Float16)(p1.x*sc); v[5]=(_Float16)(p1.y*sc); v[6]=(_Float16)(p1.z*sc); v[7]=(_Float16)(p1.w*sc);
            bf2[g][ch] = v;
        }
    }

    for (int i = tid; i < 2 * 16 * 76; i += 256)
        (&A2h2[0][0][0])[i] = (_Float16)0.0f;

    const int prow = tid >> 4, pck = tid & 15;
    {
        const half8 v = *(const half8*)(out1 + ((size_t)(b0 + prow)) * 128 + pck * 8);
        *(half8*)&A2h1[0][prow][((pck ^ (prow & 7)) * 8)] = v;
    }
    half8 pf1 = *(const half8*)(out1 + ((size_t)1 * BATCH + b0 + prow) * 128 + pck * 8);
    half8 pf2 = *(const half8*)(out1 + ((size_t)2 * BATCH + b0 + prow) * 128 + pck * 8);

    float c2[4] = {0.f, 0.f, 0.f, 0.f};
    __syncthreads();

    int cur = 0;
    for (int t = 0; t < TS; ++t) {
        const int nxt = cur ^ 1;
        f32x4 z[4];
#pragma unroll
        for (int g = 0; g < 4; ++g) z[g] = (f32x4){bias2[g], bias2[g], bias2[g], bias2[g]};
#pragma unroll
        for (int ch = 0; ch < 6; ++ch) {
            half8 a;
            if (ch < 4) a = *(const half8*)&A2h1[cur][lrow][(((ch << 2) | lgrp) ^ (lrow & 7)) * 8];
            else        a = *(const half8*)&A2h2[cur][lrow][(ch - 4) * 32 + lgrp * 8];
#pragma unroll
            for (int g = 0; g < 4; ++g)
                z[g] = __builtin_amdgcn_mfma_f32_16x16x32_f16(a, bf2[g][ch], z[g], 0, 0, 0);
        }
        const int cell = w * 16 + lrow;
#pragma unroll
        for (int j = 0; j < 4; ++j) {
            const float iv = sig2 (z[0][j]);
            const float fv = sig2 (z[1][j]);
            const float gv = tanh2(z[2][j]);
            const float ov = sig2 (z[3][j]);
            const float cn = fv * c2[j] + iv * gv;
            c2[j] = cn;
            const float h = ov * tanh2(2.0f * LOG2E * cn);
            const int m = (lgrp << 2) | j;
            A2h2[nxt][m][cell] = (_Float16)h;
            if (t == TS - 1) h2f[m][cell] = h;
        }
        if (t + 1 < TS)
            *(half8*)&A2h1[nxt][prow][((pck ^ (prow & 7)) * 8)] = pf1;
        pf1 = pf2;
        if (t + 3 < TS)
            pf2 = *(const half8*)(out1 + ((size_t)(t + 3) * BATCH + b0 + prow) * 128 + pck * 8);
        __syncthreads();
        cur = nxt;
    }

    // ---- epilogue: LayerNorm + FC1(relu) + FC2 ----
    {
        const int m = tid >> 4, q = tid & 15;
        const float v0 = h2f[m][q * 4 + 0];
        const float v1 = h2f[m][q * 4 + 1];
        const float v2 = h2f[m][q * 4 + 2];
        const float v3 = h2f[m][q * 4 + 3];
        float s = v0 + v1 + v2 + v3;
        s += __shfl_xor(s, 1); s += __shfl_xor(s, 2);
        s += __shfl_xor(s, 4); s += __shfl_xor(s, 8);
        const float mean = s * (1.0f / 64.0f);
        const float d0 = v0 - mean, d1 = v1 - mean, d2 = v2 - mean, d3 = v3 - mean;
        float vs = d0 * d0 + d1 * d1 + d2 * d2 + d3 * d3;
        vs += __shfl_xor(vs, 1); vs += __shfl_xor(vs, 2);
        vs += __shfl_xor(vs, 4); vs += __shfl_xor(vs, 8);
        const float rstd = rsqrtf(vs * (1.0f / 64.0f) + 1e-5f);
        const int i0 = q * 4;
        nrm[m][i0 + 0] = d0 * rstd * gamma[i0 + 0] + beta[i0 + 0];
        nrm[m][i0 + 1] = d1 * rstd * gamma[i0 + 1] + beta[i0 + 1];
        nrm[m][i0 + 2] = d2 * rstd * gamma[i0 + 2] + beta[i0 + 2];
        nrm[m][i0 + 3] = d3 * rstd * gamma[i0 + 3] + beta[i0 + 3];
    }
    __syncthreads();
    {
        const int o = tid & 31;
        const int mbase = tid >> 5;   // 0..7
#pragma unroll
        for (int rr = 0; rr < 2; ++rr) {
            const int m = mbase + rr * 8;
            float acc = b1fc[o];
#pragma unroll 8
            for (int k = 0; k < 64; ++k) acc += nrm[m][k] * W1fc[o * 64 + k];
            const float hv = fmaxf(acc, 0.0f);
            float p = hv * W2fc[o];
            p += __shfl_xor(p, 1); p += __shfl_xor(p, 2);
            p += __shfl_xor(p, 4); p += __shfl_xor(p, 8); p += __shfl_xor(p, 16);
            if (o == 0) out[b0 + m] = p + b2fc[0];
        }
    }
}

extern "C" void kernel_launch(void* const* d_in, const int* in_sizes, int n_in,
                              void* d_out, int out_size, void* d_ws, size_t ws_size,
                              hipStream_t stream) {
    (void)in_sizes; (void)n_in; (void)ws_size; (void)out_size;
    const float* x_p    = (const float*)d_in[0];
    const float* Wih1_p = (const float*)d_in[1];
    const float* Whh1_p = (const float*)d_in[2];
    const float* bih1_p = (const float*)d_in[3];
    const float* bhh1_p = (const float*)d_in[4];
    const float* Wih2_p = (const float*)d_in[5];
    const float* Whh2_p = (const float*)d_in[6];
    const float* bih2_p = (const float*)d_in[7];
    const float* bhh2_p = (const float*)d_in[8];
    const float* gamma_p = (const float*)d_in[9];
    const float* beta_p  = (const float*)d_in[10];
    const float* W1_p   = (const float*)d_in[11];
    const float* b1_p   = (const float*)d_in[12];
    const float* W2_p   = (const float*)d_in[13];
    const float* b2_p   = (const float*)d_in[14];
    float* out_p = (float*)d_out;

    _Float16* out1 = (_Float16*)d_ws;   // 20*8192*128*2 = 41.9 MB

    lstm1_kernel<<<dim3(BATCH / 16), dim3(512), 0, stream>>>(
        x_p, Wih1_p, Whh1_p, bih1_p, bhh1_p, out1);
    lstm2_head_kernel<<<dim3(BATCH / 16), dim3(256), 0, stream>>>(
        out1, Wih2_p, Whh2_p, bih2_p, bhh2_p,
        gamma_p, beta_p, W1_p, b1_p, W2_p, b2_p, out_p);
}

// Round 7
// 77.854 us; speedup vs baseline: 1.4683x; 1.2512x over previous
//
#include <hip/hip_runtime.h>

#define TS 20
#define BATCH 8192
#define LOG2E 1.4426950408889634f

typedef _Float16 half8 __attribute__((ext_vector_type(8)));
typedef float f32x4 __attribute__((ext_vector_type(4)));

__device__ __forceinline__ float fexp2(float x) {
#if __has_builtin(__builtin_amdgcn_exp2f)
    return __builtin_amdgcn_exp2f(x);
#else
    return exp2f(x);
#endif
}
// weights pre-scaled by log2e (sig) / 2log2e (tanh):
__device__ __forceinline__ float sig2(float zp)  { return __builtin_amdgcn_rcpf(1.0f + fexp2(-zp)); }
__device__ __forceinline__ float tanh2(float zp) { return 1.0f - 2.0f * __builtin_amdgcn_rcpf(1.0f + fexp2(zp)); }
// row swizzle for 16B LDS units
__device__ __forceinline__ int swz(int r) { return (r & 7) ^ (((r >> 3) & 1) << 2); }

// ============ Fully fused: LSTM1 + LSTM2 + LN + FC, one kernel ============
// BT=32 rows/block, grid=256 (1 block/CU, ONE dispatch round), 8 waves.
// Per step: phase A = L1 for 32 rows (each wave: its 16 cells x 4 gates x 2 M-tiles),
//           ONE barrier,
//           phase B = L2 for 32 rows (wave w: M-tile w>>2, cellgroup w&3).
// All state LDS/registers; loop has ZERO global memory ops -> barriers drain lgkm only.
// launch_bounds(512,1): measured model says 2nd arg ~ blocks/CU -> VGPR cap 256 (avoid spill).
extern "C" __global__ __launch_bounds__(512, 1)
void fused_lstm_kernel(const float* __restrict__ x,
                       const float* __restrict__ Wih1, const float* __restrict__ Whh1,
                       const float* __restrict__ bih1, const float* __restrict__ bhh1,
                       const float* __restrict__ Wih2, const float* __restrict__ Whh2,
                       const float* __restrict__ bih2, const float* __restrict__ bhh2,
                       const float* __restrict__ gamma, const float* __restrict__ beta,
                       const float* __restrict__ W1fc, const float* __restrict__ b1fc,
                       const float* __restrict__ W2fc, const float* __restrict__ b2fc,
                       float* __restrict__ out)
{
    __shared__ __align__(16) _Float16 bf2l[4 * 4 * 6 * 64 * 8];  // L2 weight frags [cg][g][ch][lane] : 96 KB
    __shared__ __align__(16) _Float16 Hb[2][2][16][128];         // h1 dbuf [slot][tile][row][cell^swz] : 16 KB
    __shared__ __align__(16) _Float16 Hc[2][2][16][72];          // h2 dbuf [slot][tile][row][cell], 144B stride : 9 KB
    __shared__ __align__(16) _Float16 Xb[32][328];               // x fp16 [row][t*16+i], 656B stride : 20.5 KB
    __shared__ float h2f[32][68];                                // final h2 (f32) for LN/FC : 8.5 KB

    const int tid  = threadIdx.x;
    const int lane = tid & 63;
    const int w    = tid >> 6;     // 0..7
    const int lrow = lane & 15;
    const int lgrp = lane >> 4;    // 0..3
    const int b0   = blockIdx.x * 32;

    // ---- L1 weights in VGPRs (80), pre-scaled ----
    half8 bf[4][5];
    float bias1[4];
#pragma unroll
    for (int g = 0; g < 4; ++g) {
        const float sc = (g == 2) ? 2.0f * LOG2E : LOG2E;
        const int n = g * 128 + w * 16 + lrow;
        bias1[g] = (bih1[n] + bhh1[n]) * sc;
#pragma unroll
        for (int ch = 0; ch < 5; ++ch) {
            half8 v;
            if (ch < 4) {
                const float4 p0 = *(const float4*)&Whh1[n * 128 + ch * 32 + lgrp * 8];
                const float4 p1 = *(const float4*)&Whh1[n * 128 + ch * 32 + lgrp * 8 + 4];
                v[0]=(_Float16)(p0.x*sc); v[1]=(_Float16)(p0.y*sc); v[2]=(_Float16)(p0.z*sc); v[3]=(_Float16)(p0.w*sc);
                v[4]=(_Float16)(p1.x*sc); v[5]=(_Float16)(p1.y*sc); v[6]=(_Float16)(p1.z*sc); v[7]=(_Float16)(p1.w*sc);
            } else if (lgrp < 2) {
                const float4 p0 = *(const float4*)&Wih1[n * 16 + lgrp * 8];
                const float4 p1 = *(const float4*)&Wih1[n * 16 + lgrp * 8 + 4];
                v[0]=(_Float16)(p0.x*sc); v[1]=(_Float16)(p0.y*sc); v[2]=(_Float16)(p0.z*sc); v[3]=(_Float16)(p0.w*sc);
                v[4]=(_Float16)(p1.x*sc); v[5]=(_Float16)(p1.y*sc); v[6]=(_Float16)(p1.z*sc); v[7]=(_Float16)(p1.w*sc);
            } else {
#pragma unroll
                for (int j = 0; j < 8; ++j) v[j] = (_Float16)0.0f;
            }
            bf[g][ch] = v;
        }
    }

    // ---- L2 bias (all waves; cellgroup = w&3) ----
    const int cg = w & 3;
    const int mt = w >> 2;
    float bias2[4];
#pragma unroll
    for (int g = 0; g < 4; ++g) {
        const float sc = (g == 2) ? 2.0f * LOG2E : LOG2E;
        const int n = g * 64 + cg * 16 + lrow;
        bias2[g] = (bih2[n] + bhh2[n]) * sc;
    }
    // ---- L2 weight frags -> LDS (waves 0..3 stage cellgroup w) ----
    if (w < 4) {
#pragma unroll
        for (int g = 0; g < 4; ++g) {
            const float sc = (g == 2) ? 2.0f * LOG2E : LOG2E;
            const int n = g * 64 + w * 16 + lrow;
#pragma unroll
            for (int ch = 0; ch < 6; ++ch) {
                const float4 p0 = (ch < 4) ? *(const float4*)&Wih2[n * 128 + ch * 32 + lgrp * 8]
                                           : *(const float4*)&Whh2[n * 64 + (ch - 4) * 32 + lgrp * 8];
                const float4 p1 = (ch < 4) ? *(const float4*)&Wih2[n * 128 + ch * 32 + lgrp * 8 + 4]
                                           : *(const float4*)&Whh2[n * 64 + (ch - 4) * 32 + lgrp * 8 + 4];
                half8 v;
                v[0]=(_Float16)(p0.x*sc); v[1]=(_Float16)(p0.y*sc); v[2]=(_Float16)(p0.z*sc); v[3]=(_Float16)(p0.w*sc);
                v[4]=(_Float16)(p1.x*sc); v[5]=(_Float16)(p1.y*sc); v[6]=(_Float16)(p1.z*sc); v[7]=(_Float16)(p1.w*sc);
                ((half8*)bf2l)[((w * 4 + g) * 6 + ch) * 64 + lane] = v;
            }
        }
    }

    // ---- zero h-state, stage x as fp16 ----
    for (int i = tid; i < 2 * 2 * 16 * 128; i += 512) (&Hb[0][0][0][0])[i] = (_Float16)0.0f;
    for (int i = tid; i < 2 * 2 * 16 * 72;  i += 512) (&Hc[0][0][0][0])[i] = (_Float16)0.0f;
    for (int i = tid; i < 32 * 320; i += 512) {
        const int r = i / 320, k = i % 320;
        Xb[r][k] = (_Float16)x[(size_t)(b0 + r) * 320 + k];
    }
    half8 kzero;
#pragma unroll
    for (int j = 0; j < 8; ++j) kzero[j] = (_Float16)0.0f;

    float c1[2][4] = {{0.f,0.f,0.f,0.f},{0.f,0.f,0.f,0.f}};
    float c2[4] = {0.f, 0.f, 0.f, 0.f};
    const int hu  = (w << 1) | (lrow >> 3);   // 16B unit of this lane's L1 cell
    const int hlo = lrow & 7;
    const int szr = swz(lrow);
    const int cell2 = (cg << 4) | lrow;       // this lane's L2 cell

    __syncthreads();

    for (int t = 0; t < TS; ++t) {
        const int s = t & 1;
        // ================= phase A: layer-1 for both M-tiles =================
        f32x4 z[2][4];
#pragma unroll
        for (int tile = 0; tile < 2; ++tile)
#pragma unroll
            for (int g = 0; g < 4; ++g) z[tile][g] = (f32x4){bias1[g], bias1[g], bias1[g], bias1[g]};
#pragma unroll
        for (int ch = 0; ch < 5; ++ch) {
#pragma unroll
            for (int tile = 0; tile < 2; ++tile) {
                half8 a;
                if (ch < 4) a = *(const half8*)&Hb[s ^ 1][tile][lrow][(((ch << 2) | lgrp) ^ szr) * 8];
                else        a = (lgrp < 2) ? *(const half8*)&Xb[tile * 16 + lrow][t * 16 + lgrp * 8] : kzero;
#pragma unroll
                for (int g = 0; g < 4; ++g)
                    z[tile][g] = __builtin_amdgcn_mfma_f32_16x16x32_f16(a, bf[g][ch], z[tile][g], 0, 0, 0);
            }
        }
#pragma unroll
        for (int tile = 0; tile < 2; ++tile)
#pragma unroll
            for (int j = 0; j < 4; ++j) {
                const float iv = sig2 (z[tile][0][j]);
                const float fv = sig2 (z[tile][1][j]);
                const float gv = tanh2(z[tile][2][j]);
                const float ov = sig2 (z[tile][3][j]);
                const float cn = fv * c1[tile][j] + iv * gv;
                c1[tile][j] = cn;
                const float h = ov * tanh2(2.0f * LOG2E * cn);
                const int m = (lgrp << 2) | j;
                Hb[s][tile][m][((hu ^ swz(m)) << 3) | hlo] = (_Float16)h;
            }
        __syncthreads();   // h1(t) visible; ONLY barrier per step (dbuf analysis)
        // ================= phase B: layer-2 (wave: tile mt, cells cg*16..) =================
        {
            half8 a2[6];
#pragma unroll
            for (int ch = 0; ch < 4; ++ch)
                a2[ch] = *(const half8*)&Hb[s][mt][lrow][(((ch << 2) | lgrp) ^ szr) * 8];
#pragma unroll
            for (int ch = 4; ch < 6; ++ch)
                a2[ch] = *(const half8*)&Hc[s ^ 1][mt][lrow][(ch - 4) * 32 + lgrp * 8];
            f32x4 z2[4];
#pragma unroll
            for (int g = 0; g < 4; ++g) {
                f32x4 acc = {bias2[g], bias2[g], bias2[g], bias2[g]};
#pragma unroll
                for (int ch = 0; ch < 6; ++ch) {
                    const half8 bfrag = ((const half8*)bf2l)[((cg * 4 + g) * 6 + ch) * 64 + lane];
                    acc = __builtin_amdgcn_mfma_f32_16x16x32_f16(a2[ch], bfrag, acc, 0, 0, 0);
                }
                z2[g] = acc;
            }
#pragma unroll
            for (int j = 0; j < 4; ++j) {
                const float iv = sig2 (z2[0][j]);
                const float fv = sig2 (z2[1][j]);
                const float gv = tanh2(z2[2][j]);
                const float ov = sig2 (z2[3][j]);
                const float cn = fv * c2[j] + iv * gv;
                c2[j] = cn;
                const float h = ov * tanh2(2.0f * LOG2E * cn);
                const int m = (lgrp << 2) | j;
                Hc[s][mt][m][cell2] = (_Float16)h;
                if (t == TS - 1) h2f[(mt << 4) | m][cell2] = h;
            }
        }
        // no barrier here: next A writes Hb[s^1] / reads Hb[s],Xb; B wrote Hc[s] read only
        // after the NEXT barrier. All same-window accesses are disjoint.
    }
    __syncthreads();

    // ---- epilogue: LayerNorm (in-place) + FC1(relu) + FC2, 32 rows ----
    {
        const int m = tid >> 4, q = tid & 15;
        const float v0 = h2f[m][q * 4 + 0];
        const float v1 = h2f[m][q * 4 + 1];
        const float v2 = h2f[m][q * 4 + 2];
        const float v3 = h2f[m][q * 4 + 3];
        float ssum = v0 + v1 + v2 + v3;
        ssum += __shfl_xor(ssum, 1); ssum += __shfl_xor(ssum, 2);
        ssum += __shfl_xor(ssum, 4); ssum += __shfl_xor(ssum, 8);
        const float mean = ssum * (1.0f / 64.0f);
        const float d0 = v0 - mean, d1 = v1 - mean, d2 = v2 - mean, d3 = v3 - mean;
        float vs = d0 * d0 + d1 * d1 + d2 * d2 + d3 * d3;
        vs += __shfl_xor(vs, 1); vs += __shfl_xor(vs, 2);
        vs += __shfl_xor(vs, 4); vs += __shfl_xor(vs, 8);
        const float rstd = rsqrtf(vs * (1.0f / 64.0f) + 1e-5f);
        const int i0 = q * 4;
        h2f[m][i0 + 0] = d0 * rstd * gamma[i0 + 0] + beta[i0 + 0];
        h2f[m][i0 + 1] = d1 * rstd * gamma[i0 + 1] + beta[i0 + 1];
        h2f[m][i0 + 2] = d2 * rstd * gamma[i0 + 2] + beta[i0 + 2];
        h2f[m][i0 + 3] = d3 * rstd * gamma[i0 + 3] + beta[i0 + 3];
    }
    __syncthreads();
    {
        const int o = tid & 31;
        const int mgrp = tid >> 5;    // 0..15
#pragma unroll
        for (int rr = 0; rr < 2; ++rr) {
            const int m = mgrp + rr * 16;
            float acc = b1fc[o];
#pragma unroll 8
            for (int k = 0; k < 64; ++k) acc += h2f[m][k] * W1fc[o * 64 + k];
            const float hv = fmaxf(acc, 0.0f);
            float p = hv * W2fc[o];
            p += __shfl_xor(p, 1); p += __shfl_xor(p, 2);
            p += __shfl_xor(p, 4); p += __shfl_xor(p, 8); p += __shfl_xor(p, 16);
            if (o == 0) out[b0 + m] = p + b2fc[0];
        }
    }
}

extern "C" void kernel_launch(void* const* d_in, const int* in_sizes, int n_in,
                              void* d_out, int out_size, void* d_ws, size_t ws_size,
                              hipStream_t stream) {
    (void)in_sizes; (void)n_in; (void)d_ws; (void)ws_size; (void)out_size;
    const float* x_p    = (const float*)d_in[0];
    const float* Wih1_p = (const float*)d_in[1];
    const float* Whh1_p = (const float*)d_in[2];
    const float* bih1_p = (const float*)d_in[3];
    const float* bhh1_p = (const float*)d_in[4];
    const float* Wih2_p = (const float*)d_in[5];
    const float* Whh2_p = (const float*)d_in[6];
    const float* bih2_p = (const float*)d_in[7];
    const float* bhh2_p = (const float*)d_in[8];
    const float* gamma_p = (const float*)d_in[9];
    const float* beta_p  = (const float*)d_in[10];
    const float* W1_p   = (const float*)d_in[11];
    const float* b1_p   = (const float*)d_in[12];
    const float* W2_p   = (const float*)d_in[13];
    const float* b2_p   = (const float*)d_in[14];
    float* out_p = (float*)d_out;

    fused_lstm_kernel<<<dim3(BATCH / 32), dim3(512), 0, stream>>>(
        x_p, Wih1_p, Whh1_p, bih1_p, bhh1_p,
        Wih2_p, Whh2_p, bih2_p, bhh2_p,
        gamma_p, beta_p, W1_p, b1_p, W2_p, b2_p, out_p);
}